// Round 4
// baseline (487.418 us; speedup 1.0000x reference)
//
#include <hip/hip_runtime.h>
#include <cstdint>
#include <cstddef>

typedef _Float16 half8 __attribute__((ext_vector_type(8)));
typedef _Float16 half4 __attribute__((ext_vector_type(4)));
typedef float f32x4 __attribute__((ext_vector_type(4)));

// async global->LDS, 16B per lane; LDS dest must be wave-uniform base + lane*16
#define GLDS16(g, l) __builtin_amdgcn_global_load_lds( \
    (__attribute__((address_space(1))) void*)(g), \
    (__attribute__((address_space(3))) void*)(l), 16, 0, 0)

// raw barrier preceded by LDS-drain only (global stores stay in flight)
#define LBAR() do { asm volatile("s_waitcnt lgkmcnt(0)" ::: "memory"); \
                    __builtin_amdgcn_s_barrier(); } while (0)

// phase boilerplate: pin reads+staging before barrier, MFMA cluster after
#define PH_MID() do { __builtin_amdgcn_sched_barrier(0); \
                      __builtin_amdgcn_s_barrier(); \
                      __builtin_amdgcn_sched_barrier(0); \
                      __builtin_amdgcn_s_setprio(1); } while (0)
#define PH_END() do { __builtin_amdgcn_s_setprio(0); \
                      __builtin_amdgcn_sched_barrier(0); \
                      __builtin_amdgcn_s_barrier(); } while (0)

// ---------------------------------------------------------------------------
// fp32 -> fp16 convert
// ---------------------------------------------------------------------------
__global__ __launch_bounds__(256) void cvt_f32_f16(const float* __restrict__ src,
                                                   _Float16* __restrict__ dst, int n) {
  int i = (blockIdx.x * 256 + threadIdx.x) * 8;
  if (i >= n) return;
  float4 a = *(const float4*)(src + i);
  float4 b = *(const float4*)(src + i + 4);
  half8 h;
  h[0] = (_Float16)a.x; h[1] = (_Float16)a.y; h[2] = (_Float16)a.z; h[3] = (_Float16)a.w;
  h[4] = (_Float16)b.x; h[5] = (_Float16)b.y; h[6] = (_Float16)b.z; h[7] = (_Float16)b.w;
  *(half8*)(dst + i) = h;
}

// ---------------------------------------------------------------------------
// QKV GEMM (unchanged from R3): 256x256 tile, BK=64, 8 waves, 8-phase.
// ---------------------------------------------------------------------------
template<int NOUT, int NT, bool BIAS>
__global__ __launch_bounds__(512, 2) void gemm_bt(const _Float16* __restrict__ A,
                                                  const _Float16* __restrict__ Bw,
                                                  const float* __restrict__ bias,
                                                  void* __restrict__ Cout) {
  constexpr int K = 512;
  __shared__ union {
    _Float16 S[2][2][16384];       // [buf parity][A=0/B=1][256x64 fragment-order]
    float E[2][16][264];           // epilogue staging
  } u;
  const int id  = blockIdx.x;
  const int xcd = id & 7;
  const int jj  = id >> 3;
  const int by  = (jj / NT) * 8 + xcd;
  const int bx  = jj % NT;
  const int m_base = by * 256, n_base = bx * 256;

  const int t    = threadIdx.x;    // 0..511
  const int lane = t & 63;
  const int wid  = t >> 6;         // 0..7
  const int wm   = wid & 1;
  const int wn   = wid >> 1;
  const int cl   = lane & 15, q = lane >> 4;

  f32x4 acc[8][4] = {};

  const int r0 = ((t >> 7) << 4) | (t & 15);
  const int c0 = (t >> 4) & 7;
  const _Float16* aR = A  + (size_t)(m_base + r0) * K + c0 * 8;
  const _Float16* bR = Bw + (size_t)(n_base + r0) * K + c0 * 8;
  char* Sb = (char*)&u.S[0][0][0];

  auto stageA = [&](int p, int h, int kt) {
    char* dst = Sb + p * 65536 + h * 16384 + t * 16;
    const _Float16* s = aR + (size_t)(h * 128) * K + kt * 64;
    GLDS16(s, dst);
    GLDS16(s + (size_t)64 * K, dst + 8192);
  };
  auto stageB = [&](int p, int h, int kt) {
    char* dst = Sb + p * 65536 + 32768 + h * 16384 + t * 16;
    const _Float16* s = bR + (size_t)(h * 128) * K + kt * 64;
    GLDS16(s, dst);
    GLDS16(s + (size_t)64 * K, dst + 8192);
  };

#define QUAD(AM, BN, BF) \
  _Pragma("unroll") for (int i_ = 0; i_ < 4; ++i_) \
  _Pragma("unroll") for (int j_ = 0; j_ < 2; ++j_) \
  _Pragma("unroll") for (int kk_ = 0; kk_ < 2; ++kk_) \
    acc[(AM)*4 + i_][(BN)*2 + j_] = __builtin_amdgcn_mfma_f32_16x16x32_f16( \
        af[i_][kk_], BF[j_][kk_], acc[(AM)*4 + i_][(BN)*2 + j_], 0, 0, 0);

  stageA(0, 0, 0); stageA(0, 1, 0); stageB(0, 0, 0); stageB(0, 1, 0);
  stageB(1, 0, 1); stageB(1, 1, 1);
  asm volatile("s_waitcnt vmcnt(4)" ::: "memory");
  __builtin_amdgcn_s_barrier();

  half8 af[4][2], bf0[2][2], bf1[2][2];
#pragma unroll
  for (int c = 0; c < 8; ++c) {
    const int p = c & 1;
    const char* aB = (const char*)u.S[p][0] + wm * 16384 + lane * 16;
    const char* bB = (const char*)u.S[p][1] + wn * 8192 + lane * 16;

#pragma unroll
    for (int fm = 0; fm < 4; ++fm)
#pragma unroll
      for (int kk = 0; kk < 2; ++kk)
        af[fm][kk] = *(const half8*)(aB + fm * 2048 + kk * 1024);
#pragma unroll
    for (int fn = 0; fn < 2; ++fn)
#pragma unroll
      for (int kk = 0; kk < 2; ++kk)
        bf0[fn][kk] = *(const half8*)(bB + fn * 2048 + kk * 1024);
    if (c + 1 < 8) stageA(p ^ 1, 0, c + 1);
    PH_MID();
    QUAD(0, 0, bf0);
    PH_END();

#pragma unroll
    for (int fn = 0; fn < 2; ++fn)
#pragma unroll
      for (int kk = 0; kk < 2; ++kk)
        bf1[fn][kk] = *(const half8*)(bB + (2 + fn) * 2048 + kk * 1024);
    if (c + 1 < 8) stageA(p ^ 1, 1, c + 1);
    PH_MID();
    QUAD(0, 1, bf1);
    PH_END();

#pragma unroll
    for (int fm = 0; fm < 4; ++fm)
#pragma unroll
      for (int kk = 0; kk < 2; ++kk)
        af[fm][kk] = *(const half8*)(aB + (4 + fm) * 2048 + kk * 1024);
    if (c + 2 < 8) stageB(p, 0, c + 2);
    PH_MID();
    QUAD(1, 1, bf1);
    PH_END();

    if (c + 2 < 8) stageB(p, 1, c + 2);
    PH_MID();
    QUAD(1, 0, bf0);
    __builtin_amdgcn_s_setprio(0);
    __builtin_amdgcn_sched_barrier(0);
    if (c < 6)       { asm volatile("s_waitcnt vmcnt(4)" ::: "memory"); }
    else if (c == 6) { asm volatile("s_waitcnt vmcnt(0)" ::: "memory"); }
    __builtin_amdgcn_s_barrier();
  }
#undef QUAD

  const int eb = t >> 8;
  const int erow = (t >> 4) & 15;
  const int ecs = t & 15;
#pragma unroll
  for (int j = 0; j < 8; ++j) {
#pragma unroll
    for (int nt = 0; nt < 4; nt++)
#pragma unroll
      for (int r = 0; r < 4; r++)
        u.E[wm][q * 4 + r][wn * 64 + nt * 16 + cl] = acc[j][nt][r];
    LBAR();
    const size_t rg = (size_t)(m_base + (eb * 8 + j) * 16 + erow);
#pragma unroll
    for (int jo = 0; jo < 4; jo++) {
      const int cc = (ecs + 16 * jo) * 4;
      float4 e = *(const float4*)&u.E[eb][erow][cc];
      if constexpr (BIAS) {
        const float4 bb = *(const float4*)(bias + n_base + cc);
        e.x += bb.x; e.y += bb.y; e.z += bb.z; e.w += bb.w;
        *(float4*)((float*)Cout + rg * NOUT + n_base + cc) = e;
      } else {
        half4 hv;
        hv[0] = (_Float16)e.x; hv[1] = (_Float16)e.y;
        hv[2] = (_Float16)e.z; hv[3] = (_Float16)e.w;
        *(half4*)((_Float16*)Cout + rg * NOUT + n_base + cc) = hv;
      }
    }
    LBAR();
  }
}

// ---------------------------------------------------------------------------
// proj GEMM: 128x128 tile, BK=64, 256 threads (4 waves 2x2), 64 KB LDS ->
// 2 independent blocks/CU. Cross-block slip replaces intra-block pipelining:
// one block's epilogue/prologue overlaps the other's K-loop (m114).
// Same fragment-order layout; 2-buffer, counted vmcnt(8) (R2-proven).
// ---------------------------------------------------------------------------
template<int NOUT, int NT, bool BIAS>
__global__ __launch_bounds__(256, 2) void gemm_bt_s(const _Float16* __restrict__ A,
                                                    const _Float16* __restrict__ Bw,
                                                    const float* __restrict__ bias,
                                                    void* __restrict__ Cout) {
  constexpr int K = 512;
  constexpr int NIT = K / 64;      // 8 K-steps
  __shared__ union {
    _Float16 S[2][2][8192];        // [buf][A=0/B=1][128x64 fragment-order]
    float E[2][16][132];           // epilogue staging (R1-proven layout)
  } u;
  const int id  = blockIdx.x;
  const int xcd = id & 7;
  const int jj  = id >> 3;
  const int by  = (jj / NT) * 8 + xcd;
  const int bx  = jj % NT;
  const int m_base = by * 128, n_base = bx * 128;

  const int t    = threadIdx.x;    // 0..255
  const int lane = t & 63;
  const int wid  = t >> 6;         // 0..3
  const int wm   = wid >> 1, wn = wid & 1;
  const int cl   = lane & 15, q = lane >> 4;

  f32x4 acc[4][4] = {};

  // staging: slot s(0..1023): band=s>>7 (16 rows x 8 chunks), r=((s>>7)<<4)|(s&15),
  // ch=(s>>4)&7; thread t owns s = t + i*256, i=0..3 -> 8 GLDS16 per K-tile.
  const _Float16* aP[4];
  const _Float16* bP[4];
#pragma unroll
  for (int i = 0; i < 4; ++i) {
    const int s = t + i * 256;
    const int r = ((s >> 7) << 4) | (s & 15), ch = (s >> 4) & 7;
    aP[i] = A  + (size_t)(m_base + r) * K + ch * 8;
    bP[i] = Bw + (size_t)(n_base + r) * K + ch * 8;
  }
  auto stage = [&](int kt) {
    const int p = kt & 1;
    const int ko = kt * 64;
#pragma unroll
    for (int i = 0; i < 4; ++i) {
      GLDS16(aP[i] + ko, (char*)&u.S[p][0][0] + (t + i * 256) * 16);
      GLDS16(bP[i] + ko, (char*)&u.S[p][1][0] + (t + i * 256) * 16);
    }
  };

  stage(0);
#pragma unroll
  for (int k = 0; k < NIT; ++k) {
    // stage k+1 (8 loads), then wait the 8 older loads of tile k
    if (k + 1 < NIT) { stage(k + 1); asm volatile("s_waitcnt vmcnt(8)" ::: "memory"); }
    else             { asm volatile("s_waitcnt vmcnt(0)" ::: "memory"); }
    __builtin_amdgcn_s_barrier();
    asm volatile("" ::: "memory");   // no LDS read hoisted above the barrier

    const _Float16* As = &u.S[k & 1][0][0];
    const _Float16* Bs = &u.S[k & 1][1][0];
    half8 af[4][2], bf[4][2];
#pragma unroll
    for (int i = 0; i < 4; i++)
#pragma unroll
      for (int kk = 0; kk < 2; kk++) {
        af[i][kk] = *(const half8*)(As + (wm * 4 + i) * 1024 + kk * 512 + lane * 8);
        bf[i][kk] = *(const half8*)(Bs + (wn * 4 + i) * 1024 + kk * 512 + lane * 8);
      }
#pragma unroll
    for (int mt = 0; mt < 4; mt++)
#pragma unroll
      for (int nt = 0; nt < 4; nt++)
#pragma unroll
        for (int kk = 0; kk < 2; kk++)
          acc[mt][nt] = __builtin_amdgcn_mfma_f32_16x16x32_f16(af[mt][kk], bf[nt][kk],
                                                               acc[mt][nt], 0, 0, 0);
    __builtin_amdgcn_s_barrier();  // all reads of buf[k&1] done before re-stage
  }

  // epilogue (R1-proven conflict-free pattern)
  const int ebnd = t >> 7, erow = (t >> 3) & 15, ecs = t & 7;
#pragma unroll
  for (int mt = 0; mt < 4; mt++) {
#pragma unroll
    for (int nt = 0; nt < 4; nt++)
#pragma unroll
      for (int r = 0; r < 4; r++)
        u.E[wm][q * 4 + r][wn * 64 + nt * 16 + cl] = acc[mt][nt][r];
    LBAR();
    const size_t rg = (size_t)(m_base + ebnd * 64 + mt * 16 + erow);
#pragma unroll
    for (int j = 0; j < 4; j++) {
      const int ch = ((ecs - erow) & 7) + 8 * j;
      const int cc = ch * 4;
      float4 e = *(const float4*)&u.E[ebnd][erow][cc];
      if constexpr (BIAS) {
        const float4 bb = *(const float4*)(bias + n_base + cc);
        e.x += bb.x; e.y += bb.y; e.z += bb.z; e.w += bb.w;
        *(float4*)((float*)Cout + rg * NOUT + n_base + cc) = e;
      } else {
        half4 hv;
        hv[0] = (_Float16)e.x; hv[1] = (_Float16)e.y;
        hv[2] = (_Float16)e.z; hv[3] = (_Float16)e.w;
        *(half4*)((_Float16*)Cout + rg * NOUT + n_base + cc) = hv;
      }
    }
    LBAR();
  }
}

// ---------------------------------------------------------------------------
// Windowed attention: one block per (head h, window b). W=64, hd=64.
// Changes vs R3: Q loaded DIRECTLY into registers (per-lane fragment address
// pattern is identical to what GLDS staging issued anyway -> same memory
// behavior, no LDS round-trip); Os dropped (direct stores from acc).
// LDS 43.6 -> 26 KB => 5 blocks/CU (was 3): latency hiding is the lever.
// ---------------------------------------------------------------------------
__global__ __launch_bounds__(256, 5) void attn_win(const _Float16* __restrict__ QKV,
                                                   _Float16* __restrict__ Out) {
  __shared__ _Float16 Ks[4096];
  __shared__ _Float16 Vt[64][72];   // V transposed: Vt[e][j], padded rows
  __shared__ _Float16 Ps[64][72];   // softmax probs
  const int h = blockIdx.x, b = blockIdx.y;
  const int t = threadIdx.x;
  const int lane = t & 63, wid = t >> 6;
  const int cl = lane & 15, q = lane >> 4;
  const int m0 = wid * 16;          // wave's 16 query rows
  const int lane8 = lane * 8;

  // ---- stage K (async, fragment order) and V (manual transpose) ----
  {
    const int s0 = t, s1 = t + 256;
    const int r0 = ((s0 >> 7) << 4) | (s0 & 15), ch0 = (s0 >> 4) & 7;
    const int r1 = ((s1 >> 7) << 4) | (s1 & 15), ch1 = (s1 >> 4) & 7;
    const _Float16* g0 = QKV + (size_t)(b * 64 + r0) * 1536 + 512 + h * 64 + ch0 * 8;
    const _Float16* g1 = QKV + (size_t)(b * 64 + r1) * 1536 + 512 + h * 64 + ch1 * 8;
    GLDS16(g0, (char*)Ks + s0 * 16);
    GLDS16(g1, (char*)Ks + s1 * 16);

    const int vj = t & 63, vp = t >> 6;   // row j of V, 16-half chunk vp
    const _Float16* vsrc = QKV + (size_t)(b * 64 + vj) * 1536 + 1024 + h * 64 + vp * 16;
    half8 v0 = *(const half8*)vsrc;
    half8 v1 = *(const half8*)(vsrc + 8);
#pragma unroll
    for (int i = 0; i < 8; i++) Vt[vp * 16 + i][vj] = v0[i];
#pragma unroll
    for (int i = 0; i < 8; i++) Vt[vp * 16 + 8 + i][vj] = v1[i];
  }

  // ---- Q fragments direct to registers (A-frag: lane(cl,q) = Q[row=cl][k=q*8]) ----
  const _Float16* qsrc = QKV + (size_t)(b * 64 + m0 + cl) * 1536 + h * 64 + q * 8;
  half8 qa0 = *(const half8*)qsrc;          // k = 0..31 slice (q*8 within)
  half8 qa1 = *(const half8*)(qsrc + 32);   // k = 32..63 slice

  __syncthreads();   // K staged (vmcnt drained) + Vt written

  // ---- S = Q K^T ----
  f32x4 s[4] = {};
#pragma unroll
  for (int nt = 0; nt < 4; nt++) {
    half8 b0 = *(const half8*)(Ks + nt * 1024 + lane8);
    half8 b1 = *(const half8*)(Ks + nt * 1024 + 512 + lane8);
    s[nt] = __builtin_amdgcn_mfma_f32_16x16x32_f16(qa0, b0, s[nt], 0, 0, 0);
    s[nt] = __builtin_amdgcn_mfma_f32_16x16x32_f16(qa1, b1, s[nt], 0, 0, 0);
  }

  // ---- softmax over 64 keys per row (row=q*4+r, keys spread over cl x nt) ----
  constexpr float SC = 0.125f * 1.44269504088896340736f;  // scale * log2(e)
#pragma unroll
  for (int r = 0; r < 4; r++) {
    float mx = fmaxf(fmaxf(s[0][r], s[1][r]), fmaxf(s[2][r], s[3][r]));
    mx = fmaxf(mx, __shfl_xor(mx, 1));
    mx = fmaxf(mx, __shfl_xor(mx, 2));
    mx = fmaxf(mx, __shfl_xor(mx, 4));
    mx = fmaxf(mx, __shfl_xor(mx, 8));
    float e[4], ssum = 0.f;
#pragma unroll
    for (int nt = 0; nt < 4; nt++) { e[nt] = exp2f((s[nt][r] - mx) * SC); ssum += e[nt]; }
    ssum += __shfl_xor(ssum, 1);
    ssum += __shfl_xor(ssum, 2);
    ssum += __shfl_xor(ssum, 4);
    ssum += __shfl_xor(ssum, 8);
    float inv = 1.f / ssum;
    const int row = m0 + q * 4 + r;
#pragma unroll
    for (int nt = 0; nt < 4; nt++) Ps[row][nt * 16 + cl] = (_Float16)(e[nt] * inv);
  }
  __syncthreads();

  // ---- O = P V  (a: Ps rows; b: Vt rows = V columns; 72-pad rotates groups) ----
  f32x4 o[4] = {};
#pragma unroll
  for (int ks = 0; ks < 2; ks++) {
    half8 a = *(const half8*)&Ps[m0 + cl][ks * 32 + q * 8];
#pragma unroll
    for (int nt = 0; nt < 4; nt++) {
      half8 bb = *(const half8*)&Vt[nt * 16 + cl][ks * 32 + q * 8];
      o[nt] = __builtin_amdgcn_mfma_f32_16x16x32_f16(a, bb, o[nt], 0, 0, 0);
    }
  }

  // ---- direct store from acc (row = m0+q*4+r, col = nt*16+cl) ----
#pragma unroll
  for (int nt = 0; nt < 4; nt++)
#pragma unroll
    for (int r = 0; r < 4; r++)
      Out[(size_t)(b * 64 + m0 + q * 4 + r) * 512 + h * 64 + nt * 16 + cl] =
          (_Float16)o[nt][r];
}

// ---------------------------------------------------------------------------
extern "C" void kernel_launch(void* const* d_in, const int* in_sizes, int n_in,
                              void* d_out, int out_size, void* d_ws, size_t ws_size,
                              hipStream_t stream) {
  const float* x      = (const float*)d_in[0];   // 16*4096*512
  const float* qkv_w  = (const float*)d_in[1];   // 1536*512
  const float* proj_w = (const float*)d_in[2];   // 512*512
  const float* proj_b = (const float*)d_in[3];   // 512
  float* out = (float*)d_out;

  char* ws = (char*)d_ws;
  _Float16* QKVh = (_Float16*)ws;                 // 65536*1536 fp16 = 201,326,592 B
  _Float16* Xh   = (_Float16*)(ws + 201326592);   // 65536*512 fp16 = 67,108,864 B
  _Float16* Outh = Xh;                            // alias: Xh dead after qkv_gemm
  _Float16* Wq   = (_Float16*)(ws + 268435456);   // 1536*512 fp16
  _Float16* Wp   = (_Float16*)(ws + 270008320);   // 512*512 fp16

  cvt_f32_f16<<<16384, 256, 0, stream>>>(x, Xh, 16 * 4096 * 512);
  cvt_f32_f16<<<384, 256, 0, stream>>>(qkv_w, Wq, 1536 * 512);
  cvt_f32_f16<<<128, 256, 0, stream>>>(proj_w, Wp, 512 * 512);
  gemm_bt<1536, 6, false><<<1536, 512, 0, stream>>>(Xh, Wq, nullptr, QKVh);
  attn_win<<<dim3(8, 1024), 256, 0, stream>>>(QKVh, Outh);
  gemm_bt_s<512, 4, true><<<2048, 256, 0, stream>>>(Outh, Wp, proj_b, out);
}